// Round 7
// baseline (36.263 us; speedup 1.0000x reference)
//
#include <hip/hip_runtime.h>

// Problem constants: DIM=4096, WIDTH=4, POOL=512, BATCH=256, SEQ=16
constexpr int DIM   = 4096;
constexpr int WIDTH = 4;
constexpr int POOL  = 512;
constexpr int BATCH = 256;
constexpr int SEQ   = 16;

constexpr int S_PER       = 8;                    // seq outputs per block (half)
constexpr int D4_CHUNKS   = DIM / (4 * 256);      // 4 column-chunks per batch row
constexpr int BLK_PER_B   = D4_CHUNKS * 2;        // 8 (chunk x half)
constexpr int CONV_BLOCKS = BLK_PER_B * BATCH;    // 2048 == total grid

typedef float f32x4 __attribute__((ext_vector_type(4)));

__device__ __forceinline__ f32x4 ld4(const float* p) {
    return *reinterpret_cast<const f32x4*>(p);
}
__device__ __forceinline__ void st4(float* p, f32x4 v) {
    *reinterpret_cast<f32x4*>(p) = v;
}
// Fast SiLU: v * rcp(1 + exp(-v)); ~1ulp, invisible at bf16-grade threshold.
__device__ __forceinline__ float fast_silu(float v) {
    return v * __builtin_amdgcn_rcpf(1.0f + __expf(-v));
}

// ---------------------------------------------------------------------------
// 2048 blocks, 256 threads, no LDS, no barriers.
//   Conv part: block = (b, d-chunk, seq-half). Preload 11 rows (window + 8 x
//     rows) + weights + bias; all loads pinned before compute via
//     sched_barrier(0). Half 1's window end = x rows 13..15 -> fused state
//     scatter to out_state[idx[b]].
//   Copy part: block also copies one QUARTER of state row (blk>>2), loads
//     issued up-front (latency hidden under conv compute), stores predicated
//     on a barrier-free membership test: each lane loads int4 of idxs (64
//     lanes x 4 = all 256 indices), wave-wide __ballot OR.
//   Write sets are disjoint => no inter-block ordering needed.
// ---------------------------------------------------------------------------
__global__ __launch_bounds__(256, 4) void fused_conv_update_kernel(
    const float* __restrict__ x,           // [BATCH, SEQ, DIM]
    const float* __restrict__ conv_state,  // [POOL, WIDTH-1, DIM]
    const float* __restrict__ weight,      // [WIDTH, DIM]
    const float* __restrict__ bias,        // [DIM]
    const int*   __restrict__ idxs,        // [BATCH]
    float*       __restrict__ out,         // [BATCH, SEQ, DIM]
    float*       __restrict__ out_state)   // [POOL, WIDTH-1, DIM]
{
    const int blk   = blockIdx.x;
    const int b     = blk >> 3;               // blk / BLK_PER_B
    const int rem   = blk & 7;
    const int chunk = rem >> 1;
    const int half  = rem & 1;
    const int d     = (chunk * 256 + threadIdx.x) * 4;
    const int idx   = idxs[b];

    const float* xb = x + (size_t)b * SEQ * DIM + d;

    // ---- Issue conv loads (11 rows + 4 weights + bias) ----
    f32x4 xv[S_PER + WIDTH - 1];               // 11 rows
    if (half == 0) {
        const float* st = conv_state + (size_t)idx * (WIDTH - 1) * DIM + d;
        xv[0] = ld4(st + 0 * DIM);
        xv[1] = ld4(st + 1 * DIM);
        xv[2] = ld4(st + 2 * DIM);
#pragma unroll
        for (int t = 0; t < S_PER; ++t)
            xv[WIDTH - 1 + t] = ld4(xb + (size_t)t * DIM);
    } else {
#pragma unroll
        for (int t = 0; t < S_PER + WIDTH - 1; ++t)
            xv[t] = ld4(xb + (size_t)(S_PER - (WIDTH - 1) + t) * DIM);  // rows 5..15
    }

    const f32x4 w0 = ld4(weight + 0 * DIM + d);
    const f32x4 w1 = ld4(weight + 1 * DIM + d);
    const f32x4 w2 = ld4(weight + 2 * DIM + d);
    const f32x4 w3 = ld4(weight + 3 * DIM + d);
    const f32x4 bs = ld4(bias + d);

    // ---- Issue copy loads (one quarter of state row blk>>2) ----
    const int row = blk >> 2;                  // 2048 blocks -> 512 rows x 4
    const int q   = blk & 3;
    constexpr int Q_FLOATS = (WIDTH - 1) * DIM / 4;   // 3072 floats per quarter
    const float* csrc = conv_state + (size_t)row * (WIDTH - 1) * DIM
                      + (size_t)q * Q_FLOATS + threadIdx.x * 4;
    f32x4 c0 = ld4(csrc + 0 * 1024);
    f32x4 c1 = ld4(csrc + 1 * 1024);
    f32x4 c2 = ld4(csrc + 2 * 1024);

    // ---- Barrier-free membership test (wave-wide, no LDS) ----
    const int4 iv = *reinterpret_cast<const int4*>(idxs + (threadIdx.x & 63) * 4);
    const bool hit = (iv.x == row) | (iv.y == row) | (iv.z == row) | (iv.w == row);
    const bool skip = (__ballot(hit) != 0ull);

    // Pin all loads above this point; waitcnts still placed per first use.
    __builtin_amdgcn_sched_barrier(0);

    // ---- Conv compute + stores ----
    float* ob = out + (size_t)b * SEQ * DIM + (size_t)half * S_PER * DIM + d;
#pragma unroll
    for (int s = 0; s < S_PER; ++s) {
        f32x4 acc = bs + xv[s] * w0 + xv[s + 1] * w1 + xv[s + 2] * w2 + xv[s + 3] * w3;
        acc.x = fast_silu(acc.x);
        acc.y = fast_silu(acc.y);
        acc.z = fast_silu(acc.z);
        acc.w = fast_silu(acc.w);
        st4(ob + (size_t)s * DIM, acc);
    }

    // Half 1 owns the state scatter: xv[8..10] = x rows 13,14,15.
    if (half == 1) {
        float* sd = out_state + (size_t)idx * (WIDTH - 1) * DIM + d;
        st4(sd + 0 * DIM, xv[S_PER + 0]);
        st4(sd + 1 * DIM, xv[S_PER + 1]);
        st4(sd + 2 * DIM, xv[S_PER + 2]);
    }

    // ---- Copy stores (skipped for rows owned by the conv path) ----
    if (!skip) {
        float* cdst = out_state + (size_t)row * (WIDTH - 1) * DIM
                    + (size_t)q * Q_FLOATS + threadIdx.x * 4;
        st4(cdst + 0 * 1024, c0);
        st4(cdst + 1 * 1024, c1);
        st4(cdst + 2 * 1024, c2);
    }
}

// ---------------------------------------------------------------------------
extern "C" void kernel_launch(void* const* d_in, const int* in_sizes, int n_in,
                              void* d_out, int out_size, void* d_ws, size_t ws_size,
                              hipStream_t stream)
{
    const float* x          = (const float*)d_in[0];
    const float* conv_state = (const float*)d_in[1];
    const float* weight     = (const float*)d_in[2];
    const float* bias       = (const float*)d_in[3];
    const int*   idxs       = (const int*)  d_in[4];

    float* out       = (float*)d_out;                    // [BATCH,SEQ,DIM]
    float* out_state = out + (size_t)BATCH * SEQ * DIM;  // [POOL,WIDTH-1,DIM]

    fused_conv_update_kernel<<<CONV_BLOCKS, 256, 0, stream>>>(
        x, conv_state, weight, bias, idxs, out, out_state);
}